// Round 1
// 427.143 us; speedup vs baseline: 1.0974x; 1.0974x over previous
//
#include <hip/hip_runtime.h>
#include <hip/hip_bf16.h>
#include <stdint.h>

// ---------------------------------------------------------------------------
// Round 5: occupancy push. Round-4 structure (fragment-ordered weights,
// packed gate in VGPRs, fused final reduce) but ROWS 64 -> 32 (RT=1):
//  - per-wave state halves (acc 32 regs, gate 16, staging 16) -> fits the
//    128-reg cap of __launch_bounds__(256,4) with margin, no spills.
//  - LDS 52.7 KB -> 25.6 KB -> 4 blocks/CU. Occupancy 23% -> ~50%.
//  - NWG 2048 -> 4096 (more independent barrier chains + tail fill).
// 32x32x16 MFMA, 4 waves, one batch still maps to 8 WGs (row0>>8).
// ---------------------------------------------------------------------------

typedef __attribute__((ext_vector_type(8))) short short8_t;
typedef __attribute__((ext_vector_type(16))) float f32x16;

#define ROWS 32
#define RTILES (ROWS / 32)   // 1
#define NWG  4096            // 131072 / 32 exactly

// LDS layout (bytes)
#define PE        (ROWS * 136)   // one stage buffer, shorts (4352)
#define OFF_P     0              // P db: 2 x [32][136] = 17408 B ; alias B2 [32][264] = 16896 B
#define OFF_A     17408          // A [32][136] = 8704 B
#define OFF_MASK  26112          // 32 floats
#define LDS_TOTAL 26240

__device__ __forceinline__ short f2bf(float f) {
  union { float f; uint32_t u; } v; v.f = f;
  uint32_t r = (v.u + 0x7FFFu + ((v.u >> 16) & 1u)) >> 16;  // RNE
  return (short)r;
}
__device__ __forceinline__ float bf2f(short b) {
  union { uint32_t u; float f; } v; v.u = ((uint32_t)(uint16_t)b) << 16;
  return v.f;
}

// ---- MFMA block: A from LDS, B coalesced from fragment-ordered global ------
// Weight layout: elem off = ((cb*KT16 + ks)<<9) + lane*8 + j
//   maps to logical n = cb*32 + (lane&31), k = ks*16 + (lane>>5)*8 + j.
// A: lane n32 -> act row (rt*32+n32), k = ks*16 + q32*8 + j. Dual k-mapping
// matches B's, so any k-permutation cancels in the dot product.
template <int KT16, int KSTEPS, int CT, int RT>
__device__ __forceinline__ void gemm32(const short* actin, int Sin,
                                       const short* __restrict__ wsB, int ks0, int cb0,
                                       f32x16 (&acc)[RT][CT], int lane) {
  const int n32 = lane & 31, q32 = lane >> 5;
#pragma unroll
  for (int ks = 0; ks < KSTEPS; ++ks) {
    const int kl = ks * 16 + q32 * 8;
    short8_t b[CT];
#pragma unroll
    for (int ct = 0; ct < CT; ++ct)
      b[ct] = *(const short8_t*)(wsB + (((cb0 + ct) * KT16 + ks0 + ks) << 9) + lane * 8);
    short8_t a[RT];
#pragma unroll
    for (int rt = 0; rt < RT; ++rt)
      a[rt] = *(const short8_t*)(actin + (rt * 32 + n32) * Sin + kl);
#pragma unroll
    for (int ct = 0; ct < CT; ++ct)
#pragma unroll
      for (int rt = 0; rt < RT; ++rt)
        acc[rt][ct] = __builtin_amdgcn_mfma_f32_32x32x16_bf16(a[rt], b[ct], acc[rt][ct], 0, 0, 0);
  }
}

// C/D layout (verified m74/m101): col = lane&31, row = (reg&3)+8*(reg>>2)+4*(lane>>5)
template <int CT, int ACTF, int RT>
__device__ __forceinline__ void epi32(f32x16 (&acc)[RT][CT], short* actout, int Sout,
                                      const float* __restrict__ bias, int c0, int n32, int q32) {
#pragma unroll
  for (int ct = 0; ct < CT; ++ct) {
    const int c = c0 + ct * 32 + n32;
    const float bv = bias[c];
#pragma unroll
    for (int rt = 0; rt < RT; ++rt)
#pragma unroll
      for (int reg = 0; reg < 16; ++reg) {
        const int r = rt * 32 + (reg & 3) + 8 * (reg >> 2) + 4 * q32;
        float v = acc[rt][ct][reg] + bv;
        if (ACTF == 1) v = fmaxf(v, 0.f);
        actout[r * Sout + c] = f2bf(v);
      }
  }
}

template <int K, int N, int ACTF>
__device__ __forceinline__ void layer32(const short* actin, int Sin, short* actout, int Sout,
                                        const short* __restrict__ wsB,
                                        const float* __restrict__ bias,
                                        int wv, int lane) {
  constexpr int CT = N / 128;          // 1 (N=128) or 2 (N=256)
  const int cb0 = wv * CT;
  const int n32 = lane & 31, q32 = lane >> 5;
  f32x16 acc[RTILES][CT];
#pragma unroll
  for (int rt = 0; rt < RTILES; ++rt)
#pragma unroll
    for (int ct = 0; ct < CT; ++ct) acc[rt][ct] = (f32x16)(0.f);
  gemm32<K / 16, K / 16, CT>(actin, Sin, wsB, 0, cb0, acc, lane);
  epi32<CT, ACTF>(acc, actout, Sout, bias, cb0 * 32, n32, q32);
}

// ---- input streaming: 32 rows x 128 cols fp32 per chunk --------------------
__device__ __forceinline__ void stage_load(const float* __restrict__ src, int row0, int colbase,
                                           int tid, float4 (&v)[ROWS / 8]) {
  const int c4 = tid & 31, rb = tid >> 5;
#pragma unroll
  for (int it = 0; it < ROWS / 8; ++it)
    v[it] = *(const float4*)(src + (size_t)(row0 + rb + it * 8) * 256 + colbase + c4 * 4);
}

// mmode: 0 none, 1 init maskacc, 2 accumulate
__device__ __forceinline__ void stage_store(short* Pb, int tid, const float4 (&v)[ROWS / 8],
                                            float* maskacc, int mmode) {
  const int c4 = tid & 31, rb = tid >> 5;
#pragma unroll
  for (int it = 0; it < ROWS / 8; ++it) {
    const int r = rb + it * 8;
    short4 pk; pk.x = f2bf(v[it].x); pk.y = f2bf(v[it].y); pk.z = f2bf(v[it].z); pk.w = f2bf(v[it].w);
    *(short4*)(Pb + r * 136 + c4 * 4) = pk;
    if (mmode) {
      float s = v[it].x + v[it].y + v[it].z + v[it].w;
      s += __shfl_down(s, 16, 32);
      s += __shfl_down(s, 8, 32);
      s += __shfl_down(s, 4, 32);
      s += __shfl_down(s, 2, 32);
      s += __shfl_down(s, 1, 32);
      if (c4 == 0) {
        if (mmode == 1) maskacc[r] = s; else maskacc[r] += s;
      }
    }
  }
}

// Streamed first layer (N=128 out): chunks kc<splitc from src0, else src1.
template <int NCH, bool MASKA>
__device__ __forceinline__ void stream32(const float* __restrict__ src0,
                                         const float* __restrict__ src1, int splitc,
                                         const short* __restrict__ wsB,
                                         const float* __restrict__ bias,
                                         short* P, short* Aout, float* maskacc,
                                         int row0, int tid, int wv, int lane) {
  constexpr int KT16 = NCH * 8;
  const int n32 = lane & 31, q32 = lane >> 5;
  f32x16 acc[RTILES][1];
#pragma unroll
  for (int rt = 0; rt < RTILES; ++rt) acc[rt][0] = (f32x16)(0.f);
  float4 v[ROWS / 8];
  stage_load(src0, row0, 0, tid, v);
  stage_store(P, tid, v, maskacc, MASKA ? 1 : 0);
  __syncthreads();
#pragma unroll
  for (int kc = 0; kc < NCH; ++kc) {
    if (kc + 1 < NCH) {
      const bool lo = (kc + 1 < splitc);
      stage_load(lo ? src0 : src1, row0, (lo ? kc + 1 : kc + 1 - splitc) * 128, tid, v);
    }
    gemm32<KT16, 8, 1>(P + (kc & 1) * PE, 136, wsB, kc * 8, wv, acc, lane);
    if (kc + 1 < NCH)
      stage_store(P + ((kc + 1) & 1) * PE, tid, v, maskacc, (MASKA && kc + 1 < splitc) ? 2 : 0);
    __syncthreads();
  }
  epi32<1, 1>(acc, Aout, 136, bias, wv * 32, n32, q32);
}

// g3: K=128 N=256 sigmoid -> packed bf16 gate in VGPRs (wave-local, C-layout)
__device__ __forceinline__ void gate_layer(const short* actin, const short* __restrict__ wsB,
                                           const float* __restrict__ bias,
                                           uint32_t (&gate)[RTILES][2][8],
                                           int wv, int lane) {
  const int n32 = lane & 31;
  f32x16 acc[RTILES][2];
#pragma unroll
  for (int rt = 0; rt < RTILES; ++rt)
#pragma unroll
    for (int ct = 0; ct < 2; ++ct) acc[rt][ct] = (f32x16)(0.f);
  gemm32<8, 8, 2>(actin, 136, wsB, 0, wv * 2, acc, lane);
#pragma unroll
  for (int ct = 0; ct < 2; ++ct) {
    const float bv = bias[wv * 64 + ct * 32 + n32];
#pragma unroll
    for (int rt = 0; rt < RTILES; ++rt)
#pragma unroll
      for (int p = 0; p < 8; ++p) {
        const float g0 = 1.f / (1.f + __expf(-(acc[rt][ct][2 * p] + bv)));
        const float g1 = 1.f / (1.f + __expf(-(acc[rt][ct][2 * p + 1] + bv)));
        gate[rt][ct][p] = ((uint32_t)(uint16_t)f2bf(g1) << 16) | (uint32_t)(uint16_t)f2bf(g0);
      }
  }
}

// o3: K=128 N=256, fused mask*gate*val reduce over 32 rows + atomicAdd
__device__ __forceinline__ void final32(const short* actin, const short* __restrict__ wsB,
                                        const float* __restrict__ bias,
                                        const uint32_t (&gate)[RTILES][2][8],
                                        const float* maskacc, float* __restrict__ out,
                                        int row0, int wv, int lane) {
  const int n32 = lane & 31, q32 = lane >> 5;
  f32x16 acc[RTILES][2];
#pragma unroll
  for (int rt = 0; rt < RTILES; ++rt)
#pragma unroll
    for (int ct = 0; ct < 2; ++ct) acc[rt][ct] = (f32x16)(0.f);
  gemm32<8, 8, 2>(actin, 136, wsB, 0, wv * 2, acc, lane);

  const int b = row0 >> 8;       // 32 | 256, 8 WGs per batch
#pragma unroll
  for (int ct = 0; ct < 2; ++ct) {
    const int c = wv * 64 + ct * 32 + n32;
    const float bv = bias[c];
    float s = 0.f;
#pragma unroll
    for (int rt = 0; rt < RTILES; ++rt)
#pragma unroll
      for (int p = 0; p < 8; ++p) {
        const int r0 = rt * 32 + ((2 * p) & 3) + 8 * (p >> 1) + 4 * q32;  // reg=2p
        const float g0 = bf2f((short)(gate[rt][ct][p] & 0xFFFF));
        const float g1 = bf2f((short)(gate[rt][ct][p] >> 16));
        const float v0 = acc[rt][ct][2 * p] + bv;
        const float v1 = acc[rt][ct][2 * p + 1] + bv;
        if (maskacc[r0] > 0.f)     s += g0 * v0;
        if (maskacc[r0 + 1] > 0.f) s += g1 * v1;
      }
    s += __shfl_down(s, 32);
    if (lane < 32) atomicAdd(out + b * 256 + c, s);
  }
}

__global__ __launch_bounds__(256, 4)
void readout_main(const float* __restrict__ h0, const float* __restrict__ hT,
                  const short* __restrict__ ws,
                  const float* __restrict__ gb0, const float* __restrict__ gb1,
                  const float* __restrict__ gb2, const float* __restrict__ gb3,
                  const float* __restrict__ ob0, const float* __restrict__ ob1,
                  const float* __restrict__ ob2, const float* __restrict__ ob3,
                  float* __restrict__ out) {
  __shared__ __align__(16) char smem[LDS_TOTAL];
  short* P  = (short*)(smem + OFF_P);
  short* B2 = (short*)(smem + OFF_P);      // [32][264], aliases P (disjoint lifetimes)
  short* A  = (short*)(smem + OFF_A);      // [32][136]
  float* maskacc = (float*)(smem + OFF_MASK);

  const int tid = threadIdx.x, lane = tid & 63, wv = tid >> 6;
  const int row0 = blockIdx.x * ROWS;
  uint32_t gate[RTILES][2][8];

  // gate chain
  stream32<4, true>(h0, hT, 2, ws + 0, gb0, P, A, maskacc, row0, tid, wv, lane);
  __syncthreads();
  layer32<128, 256, 1>(A, 136, B2, 264, ws + 65536, gb1, wv, lane);
  __syncthreads();
  layer32<256, 128, 1>(B2, 264, A, 136, ws + 98304, gb2, wv, lane);
  __syncthreads();
  gate_layer(A, ws + 131072, gb3, gate, wv, lane);
  __syncthreads();
  // value chain (hT re-streamed, L3-warm)
  stream32<2, false>(hT, hT, 2, ws + 163840, ob0, P, A, maskacc, row0, tid, wv, lane);
  __syncthreads();
  layer32<128, 256, 1>(A, 136, B2, 264, ws + 196608, ob1, wv, lane);
  __syncthreads();
  layer32<256, 128, 1>(B2, 264, A, 136, ws + 229376, ob2, wv, lane);
  __syncthreads();
  final32(A, ws + 262144, ob3, gate, maskacc, out, row0, wv, lane);
}

// ---- prep: weights fp32[K][N] -> bf16 fragment-ordered; zero out -----------
// ws elem off = layer_off + ((cb*(K/16) + ks)<<9) + lanei*8 + j
//   with n = cb*32 + (lanei&31), k = ks*16 + (lanei>>5)*8 + j.
__global__ void prep(const float* __restrict__ W0, const float* __restrict__ W1,
                     const float* __restrict__ W2, const float* __restrict__ W3,
                     const float* __restrict__ W4, const float* __restrict__ W5,
                     const float* __restrict__ W6, const float* __restrict__ W7,
                     short* __restrict__ ws, float* __restrict__ out) {
  const int l = blockIdx.y;
  const int le = blockIdx.x * 256 + threadIdx.x;    // < 65536
  if (l == 1) { out[le] = 0.f; out[le + 65536] = 0.f; }
  int K, N, off; const float* W;
  switch (l) {
    case 0:  K = 512; N = 128; off = 0;      W = W0; break;
    case 1:  K = 128; N = 256; off = 65536;  W = W1; break;
    case 2:  K = 256; N = 128; off = 98304;  W = W2; break;
    case 3:  K = 128; N = 256; off = 131072; W = W3; break;
    case 4:  K = 256; N = 128; off = 163840; W = W4; break;
    case 5:  K = 128; N = 256; off = 196608; W = W5; break;
    case 6:  K = 256; N = 128; off = 229376; W = W6; break;
    default: K = 128; N = 256; off = 262144; W = W7; break;
  }
  if (le >= K * N) return;
  const int j = le & 7;
  const int lanei = (le >> 3) & 63;
  const int blk = le >> 9;
  const int kt16 = K >> 4;
  const int ks = blk % kt16, cb = blk / kt16;
  const int n = cb * 32 + (lanei & 31);
  const int k = ks * 16 + (lanei >> 5) * 8 + j;
  ws[off + le] = f2bf(W[k * N + n]);    // coalesced write, gathered read
}

extern "C" void kernel_launch(void* const* d_in, const int* in_sizes, int n_in,
                              void* d_out, int out_size, void* d_ws, size_t ws_size,
                              hipStream_t stream) {
  const float* h0  = (const float*)d_in[0];
  const float* hT  = (const float*)d_in[1];
  const float* gW0 = (const float*)d_in[2];  const float* gb0 = (const float*)d_in[3];
  const float* gW1 = (const float*)d_in[4];  const float* gb1 = (const float*)d_in[5];
  const float* gW2 = (const float*)d_in[6];  const float* gb2 = (const float*)d_in[7];
  const float* gW3 = (const float*)d_in[8];  const float* gb3 = (const float*)d_in[9];
  const float* oW0 = (const float*)d_in[10]; const float* ob0 = (const float*)d_in[11];
  const float* oW1 = (const float*)d_in[12]; const float* ob1 = (const float*)d_in[13];
  const float* oW2 = (const float*)d_in[14]; const float* ob2 = (const float*)d_in[15];
  const float* oW3 = (const float*)d_in[16]; const float* ob3 = (const float*)d_in[17];
  float* out = (float*)d_out;
  short* ws  = (short*)d_ws;   // 589824 B

  prep<<<dim3(256, 8), 256, 0, stream>>>(gW0, gW1, gW2, gW3, oW0, oW1, oW2, oW3, ws, out);
  readout_main<<<NWG, 256, 0, stream>>>(h0, hT, ws,
                                        gb0, gb1, gb2, gb3,
                                        ob0, ob1, ob2, ob3, out);
}